// Round 2
// baseline (341.447 us; speedup 1.0000x reference)
//
#include <hip/hip_runtime.h>

// DelayedXOR_SH_SNN: fused SNN scan.
//   x [B,T,I] f32, W1 [H,I], b1 [H], tau_m [H], W2 [O,H], b2 [O]
//   B=1024 T=2048 I=16 H=64 O=1, V_TH=1.0
// One 64-lane wave per batch element b; lane = hidden unit h.
// Sequential scan over T in registers; x staged via double-buffered LDS.

constexpr int Bn = 1024;
constexpr int Tn = 2048;
constexpr int In = 16;
constexpr int Hn = 64;

constexpr int CHUNK = 128;                  // timesteps staged per LDS buffer
constexpr int NCH = Tn / CHUNK;             // 16 chunks
constexpr int CHUNK_F4 = CHUNK * In / 4;    // 512 float4 per chunk
constexpr int F4_PER_LANE = CHUNK_F4 / 64;  // 8 float4 per lane staging

__global__ __launch_bounds__(64) void snn_fused_kernel(
    const float* __restrict__ x,
    const float* __restrict__ W1,
    const float* __restrict__ b1,
    const float* __restrict__ tau,
    const float* __restrict__ W2,
    const float* __restrict__ b2,
    float* __restrict__ out)
{
    const int b = blockIdx.x;
    const int lane = threadIdx.x;   // h index

    __shared__ float lds[2][CHUNK * In];

    // Per-lane weights (W1 row for this h)
    float w[In];
#pragma unroll
    for (int i = 0; i < In; ++i) w[i] = W1[lane * In + i];
    const float bias = b1[lane];

    // alpha = sigmoid(tau_m[h]); compute in f64, round once (closest to a
    // correctly-rounded f32 sigmoid; np/jax agree within ~1 ulp).
    const double td = (double)tau[lane];
    const float alpha = (float)(1.0 / (1.0 + exp(-td)));
    const float onem = __fsub_rn(1.0f, alpha);

    const float4* xg = (const float4*)(x + (size_t)b * (size_t)(Tn * In));

    // Preload chunk 0 into LDS buffer 0.
    float4 st[F4_PER_LANE];
#pragma unroll
    for (int j = 0; j < F4_PER_LANE; ++j) st[j] = xg[j * 64 + lane];
#pragma unroll
    for (int j = 0; j < F4_PER_LANE; ++j)
        ((float4*)lds[0])[j * 64 + lane] = st[j];

    float v = 0.0f, s = 0.0f, acc = 0.0f;

    for (int c = 0; c < NCH; ++c) {
        const int cur = c & 1;

        // Prefetch next chunk into registers (latency hides under compute).
        if (c + 1 < NCH) {
#pragma unroll
            for (int j = 0; j < F4_PER_LANE; ++j)
                st[j] = xg[(c + 1) * CHUNK_F4 + j * 64 + lane];
        }

        const float* xt = lds[cur];
        const bool second = (c >= NCH / 2);

#pragma unroll 4
        for (int tt = 0; tt < CHUNK; ++tt) {
            const float4* xr = (const float4*)(xt + tt * In);
            const float4 x0 = xr[0];
            const float4 x1 = xr[1];
            const float4 x2 = xr[2];
            const float4 x3 = xr[3];

            // ic = sum_i x[t,i]*w[i], strictly sequential, no fma contraction
            // (mirrors numpy einsum accumulation order).
            float ic;
            ic = __fmul_rn(x0.x, w[0]);
            ic = __fadd_rn(ic, __fmul_rn(x0.y, w[1]));
            ic = __fadd_rn(ic, __fmul_rn(x0.z, w[2]));
            ic = __fadd_rn(ic, __fmul_rn(x0.w, w[3]));
            ic = __fadd_rn(ic, __fmul_rn(x1.x, w[4]));
            ic = __fadd_rn(ic, __fmul_rn(x1.y, w[5]));
            ic = __fadd_rn(ic, __fmul_rn(x1.z, w[6]));
            ic = __fadd_rn(ic, __fmul_rn(x1.w, w[7]));
            ic = __fadd_rn(ic, __fmul_rn(x2.x, w[8]));
            ic = __fadd_rn(ic, __fmul_rn(x2.y, w[9]));
            ic = __fadd_rn(ic, __fmul_rn(x2.z, w[10]));
            ic = __fadd_rn(ic, __fmul_rn(x2.w, w[11]));
            ic = __fadd_rn(ic, __fmul_rn(x3.x, w[12]));
            ic = __fadd_rn(ic, __fmul_rn(x3.y, w[13]));
            ic = __fadd_rn(ic, __fmul_rn(x3.z, w[14]));
            ic = __fadd_rn(ic, __fmul_rn(x3.w, w[15]));
            ic = __fadd_rn(ic, bias);

            // v = alpha*v + (1-alpha)*ic - V_TH*s   (V_TH=1.0, mul exact)
            const float t1 = __fmul_rn(alpha, v);
            const float t2 = __fmul_rn(onem, ic);
            v = __fsub_rn(__fadd_rn(t1, t2), s);

            // s = (v - V_TH > 0) ? 1 : 0
            s = (__fsub_rn(v, 1.0f) > 0.0f) ? 1.0f : 0.0f;

            if (second) acc = __fadd_rn(acc, s);
        }

        // Commit prefetched registers to the other LDS buffer.
        if (c + 1 < NCH) {
#pragma unroll
            for (int j = 0; j < F4_PER_LANE; ++j)
                ((float4*)lds[cur ^ 1])[j * 64 + lane] = st[j];
        }
    }

    // out[b] = sum_h acc[h] * W2[0,h] + b2[0]  (wave butterfly reduce)
    float val = __fmul_rn(acc, W2[lane]);
#pragma unroll
    for (int off = 32; off > 0; off >>= 1)
        val = __fadd_rn(val, __shfl_down(val, off));
    if (lane == 0) out[b] = __fadd_rn(val, b2[0]);
}

extern "C" void kernel_launch(void* const* d_in, const int* in_sizes, int n_in,
                              void* d_out, int out_size, void* d_ws, size_t ws_size,
                              hipStream_t stream) {
    const float* x   = (const float*)d_in[0];
    const float* W1  = (const float*)d_in[1];
    const float* b1  = (const float*)d_in[2];
    const float* tau = (const float*)d_in[3];
    const float* W2  = (const float*)d_in[4];
    const float* b2  = (const float*)d_in[5];
    float* out = (float*)d_out;

    snn_fused_kernel<<<dim3(Bn), dim3(64), 0, stream>>>(x, W1, b1, tau, W2, b2, out);
}

// Round 3
// 319.412 us; speedup vs baseline: 1.0690x; 1.0690x over previous
//
#include <hip/hip_runtime.h>

// DelayedXOR_SH_SNN: fused SNN scan, packed-FP32 edition.
//   x [B,T,I] f32, W1 [H,I], b1 [H], tau_m [H], W2 [O,H], b2 [O]
//   B=1024 T=2048 I=16 H=64 O=1, V_TH=1.0
// One 64-lane wave per batch element b; lane = hidden unit h.
// Timesteps processed in pairs: dot(t) in lo / dot(t+1) in hi of
// <2 x float> ops -> v_pk_mul_f32 / v_pk_add_f32 (exact per-component
// IEEE rounding, same left-assoc order as numpy). Scan stays scalar.
// x staged via double-buffered LDS, TRANSPOSED [i][t] so a (t,t+1) pair
// is one aligned 8B broadcast read.

typedef float v2f __attribute__((ext_vector_type(2)));

constexpr int Bn = 1024;
constexpr int Tn = 2048;
constexpr int In = 16;

constexpr int CHUNK = 128;                  // timesteps per LDS buffer
constexpr int NCH = Tn / CHUNK;             // 16 chunks
constexpr int ROWP = CHUNK + 2;             // row pitch (dwords), even + bank-spread
constexpr int CHUNK_F4 = CHUNK * In / 4;    // 512 float4 per chunk
constexpr int F4_PER_LANE = CHUNK_F4 / 64;  // 8 float4 per lane staging

__global__ __launch_bounds__(64) void snn_fused_kernel(
    const float* __restrict__ x,
    const float* __restrict__ W1,
    const float* __restrict__ b1,
    const float* __restrict__ tau,
    const float* __restrict__ W2,
    const float* __restrict__ b2,
    float* __restrict__ out)
{
    const int b = blockIdx.x;
    const int lane = threadIdx.x;   // h index

    __shared__ float lds[2][In * ROWP];

    // Per-lane W1 row, packed (w,w) for the pk ops.
    v2f w2[In];
#pragma unroll
    for (int i = 0; i < In; ++i) {
        const float wv = W1[lane * In + i];
        w2[i].x = wv; w2[i].y = wv;
    }
    const float biasf = b1[lane];
    v2f bias2; bias2.x = biasf; bias2.y = biasf;

    // alpha = sigmoid(tau_m[h]) in f64, rounded once.
    const double td = (double)tau[lane];
    const float alpha = (float)(1.0 / (1.0 + exp(-td)));
    const float onem = __fsub_rn(1.0f, alpha);

    const float4* xg = (const float4*)(x + (size_t)b * (size_t)(Tn * In));

    // Transposed-commit bases: lane handles dwords d = j*256 + lane*4 + c.
    // i = d & 15, t = d >> 4  ->  addr = i*ROWP + t = base_c + j*16.
    int wbase[4];
#pragma unroll
    for (int c = 0; c < 4; ++c) {
        const int d0 = lane * 4 + c;
        wbase[c] = (d0 & 15) * ROWP + (d0 >> 4);
    }

    float4 st[F4_PER_LANE];

    // Preload chunk 0 into LDS buffer 0 (transposed).
#pragma unroll
    for (int j = 0; j < F4_PER_LANE; ++j) st[j] = xg[j * 64 + lane];
#pragma unroll
    for (int j = 0; j < F4_PER_LANE; ++j) {
        lds[0][wbase[0] + j * 16] = st[j].x;
        lds[0][wbase[1] + j * 16] = st[j].y;
        lds[0][wbase[2] + j * 16] = st[j].z;
        lds[0][wbase[3] + j * 16] = st[j].w;
    }

    float v = 0.0f, s = 0.0f, acc = 0.0f;

    for (int c = 0; c < NCH; ++c) {
        const int cur = c & 1;

        // Prefetch next chunk into registers.
        if (c + 1 < NCH) {
#pragma unroll
            for (int j = 0; j < F4_PER_LANE; ++j)
                st[j] = xg[(c + 1) * CHUNK_F4 + j * 64 + lane];
        }

        const float* xt = lds[cur];
        const bool second = (c >= NCH / 2);

#pragma unroll 4
        for (int tt = 0; tt < CHUNK; tt += 2) {
            // Dual dot: lo = timestep tt, hi = timestep tt+1.
            // Exact same left-assoc mul/add chain per component as numpy;
            // contraction off so no fma sneaks in.
#pragma clang fp contract(off)
            v2f a2 = (*(const v2f*)&xt[0 * ROWP + tt]) * w2[0];
#pragma unroll
            for (int i = 1; i < In; ++i)
                a2 = a2 + (*(const v2f*)&xt[i * ROWP + tt]) * w2[i];
            const v2f ic2 = a2 + bias2;

            // Scan step tt.
            {
                const float t1 = __fmul_rn(alpha, v);
                const float t2 = __fmul_rn(onem, ic2.x);
                v = __fsub_rn(__fadd_rn(t1, t2), s);
                s = (__fsub_rn(v, 1.0f) > 0.0f) ? 1.0f : 0.0f;
                if (second) acc = __fadd_rn(acc, s);
            }
            // Scan step tt+1.
            {
                const float t1 = __fmul_rn(alpha, v);
                const float t2 = __fmul_rn(onem, ic2.y);
                v = __fsub_rn(__fadd_rn(t1, t2), s);
                s = (__fsub_rn(v, 1.0f) > 0.0f) ? 1.0f : 0.0f;
                if (second) acc = __fadd_rn(acc, s);
            }
        }

        // Commit prefetched registers to the other LDS buffer (transposed).
        if (c + 1 < NCH) {
            float* dst = lds[cur ^ 1];
#pragma unroll
            for (int j = 0; j < F4_PER_LANE; ++j) {
                dst[wbase[0] + j * 16] = st[j].x;
                dst[wbase[1] + j * 16] = st[j].y;
                dst[wbase[2] + j * 16] = st[j].z;
                dst[wbase[3] + j * 16] = st[j].w;
            }
        }
    }

    // out[b] = sum_h acc[h] * W2[0,h] + b2[0]  (wave butterfly reduce)
    float val = __fmul_rn(acc, W2[lane]);
#pragma unroll
    for (int off = 32; off > 0; off >>= 1)
        val = __fadd_rn(val, __shfl_down(val, off));
    if (lane == 0) out[b] = __fadd_rn(val, b2[0]);
}

extern "C" void kernel_launch(void* const* d_in, const int* in_sizes, int n_in,
                              void* d_out, int out_size, void* d_ws, size_t ws_size,
                              hipStream_t stream) {
    const float* x   = (const float*)d_in[0];
    const float* W1  = (const float*)d_in[1];
    const float* b1  = (const float*)d_in[2];
    const float* tau = (const float*)d_in[3];
    const float* W2  = (const float*)d_in[4];
    const float* b2  = (const float*)d_in[5];
    float* out = (float*)d_out;

    snn_fused_kernel<<<dim3(Bn), dim3(64), 0, stream>>>(x, W1, b1, tau, W2, b2, out);
}